// Round 2
// 824.272 us; speedup vs baseline: 1.0038x; 1.0038x over previous
//
#include <hip/hip_runtime.h>
#include <math.h>

// ---------------------------------------------------------------------------
// GCN: x[N,128] -> conv1(W1[128,32]) -> relu -> conv2(W2[32,16]) -> fc heads
// Outputs (concat): r[N], x1f[N]
//
// Strategy: replace push-scatter (f32 atomics write-through to HBM, 400 MB of
// atomic RMW traffic per layer) with an on-device counting-sort CSR (built
// once, shared by both conv layers since the edge norm is identical) and
// pull-mode gather: one wave per destination node, zero float atomics.
//
// Workspace budget (N=100K, E=3.2M): deg 0.4 + h1 12.8 + hrelu 12.8 +
// cnt/off/cur 1.2 + epair 25.6 = ~52.8 MB. Guarded against ws_size.
// ---------------------------------------------------------------------------

#define TPB 256

__device__ __forceinline__ float atomAddF(float* p, float v) {
    return unsafeAtomicAdd(p, v);   // native global_atomic_add_f32 on gfx950
}

// cnt[dst]++ ; deg[dst] += w   (self-loop +1 added later in dinv)
__global__ __launch_bounds__(TPB) void hist_kernel(const int* __restrict__ dst,
                                                   const float* __restrict__ ew,
                                                   int* __restrict__ cnt,
                                                   float* __restrict__ deg, int E) {
    int e = blockIdx.x * TPB + threadIdx.x;
    if (e < E) {
        int d = dst[e];
        atomicAdd(&cnt[d], 1);
        atomAddF(&deg[d], ew[e]);
    }
}

// deg -> dinv = 1/sqrt(deg+1)  (in place)
__global__ __launch_bounds__(TPB) void dinv_kernel(float* __restrict__ deg, int N) {
    int i = blockIdx.x * TPB + threadIdx.x;
    if (i < N) deg[i] = 1.0f / sqrtf(deg[i] + 1.0f);
}

// Exclusive prefix sum of cnt[N] -> off[N], and cur[N] = off[N] (cursor copy).
// Single block, 1024 threads, 4 elements/thread/chunk; shfl wave scan + LDS.
__global__ __launch_bounds__(1024) void scan_kernel(const int* __restrict__ cnt,
                                                    int* __restrict__ off,
                                                    int* __restrict__ cur, int N) {
    __shared__ int wsum[16];
    __shared__ int wpre[17];            // wpre[16] = chunk total
    const int tid  = threadIdx.x;
    const int lane = tid & 63;
    const int wid  = tid >> 6;
    int carry = 0;                      // uniform across threads

    for (int base = 0; base < N; base += 4096) {
        int i0 = base + tid * 4;
        int v0 = 0, v1 = 0, v2 = 0, v3 = 0;
        if (i0 + 3 < N) {
            int4 v = *(const int4*)(cnt + i0);
            v0 = v.x; v1 = v.y; v2 = v.z; v3 = v.w;
        } else if (i0 < N) {
            v0 = cnt[i0];
            if (i0 + 1 < N) v1 = cnt[i0 + 1];
            if (i0 + 2 < N) v2 = cnt[i0 + 2];
        }
        int s = v0 + v1 + v2 + v3;

        // inclusive scan of s within the wave (64 lanes)
        int incl = s;
#pragma unroll
        for (int d = 1; d < 64; d <<= 1) {
            int t = __shfl_up(incl, d);
            if (lane >= d) incl += t;
        }
        if (lane == 63) wsum[wid] = incl;
        __syncthreads();

        if (wid == 0 && lane < 16) {
            int ws = wsum[lane];
            int wi = ws;
#pragma unroll
            for (int d = 1; d < 16; d <<= 1) {
                int t = __shfl_up(wi, d);
                if (lane >= d) wi += t;
            }
            wpre[lane] = wi - ws;       // exclusive wave prefix
            if (lane == 15) wpre[16] = wi;  // chunk total
        }
        __syncthreads();

        int excl = carry + wpre[wid] + (incl - s);
        int o0 = excl;
        int o1 = o0 + v0;
        int o2 = o1 + v1;
        int o3 = o2 + v2;
        if (i0     < N) { off[i0]     = o0; cur[i0]     = o0; }
        if (i0 + 1 < N) { off[i0 + 1] = o1; cur[i0 + 1] = o1; }
        if (i0 + 2 < N) { off[i0 + 2] = o2; cur[i0 + 2] = o2; }
        if (i0 + 3 < N) { off[i0 + 3] = o3; cur[i0 + 3] = o3; }

        carry += wpre[16];
        __syncthreads();                // protect wsum/wpre before next chunk
    }
}

// Place (src, norm) per destination: epair[pos] = {src, dinv[s]*w*dinv[d]}
__global__ __launch_bounds__(TPB) void reorder_kernel(const int* __restrict__ src,
                                                      const int* __restrict__ dst,
                                                      const float* __restrict__ ew,
                                                      const float* __restrict__ dinv,
                                                      int* __restrict__ cur,
                                                      int2* __restrict__ epair, int E) {
    int e = blockIdx.x * TPB + threadIdx.x;
    if (e >= E) return;
    int s = src[e], d = dst[e];
    int pos = atomicAdd(&cur[d], 1);
    float norm = dinv[s] * ew[e] * dinv[d];
    int2 p;
    p.x = s;
    p.y = __float_as_int(norm);
    epair[pos] = p;
}

// h[N,32] = x[N,128] @ W[128,32].  Block: 32 nodes, 256 threads.
__global__ __launch_bounds__(TPB) void gemm1_kernel(const float* __restrict__ x,
                                                    const float* __restrict__ W,
                                                    float* __restrict__ h, int N) {
    __shared__ float Ws[128 * 32];     // 16 KB
    __shared__ float xs[32 * 129];     // padded stride 129 to kill bank conflicts
    const int tid = threadIdx.x;
    const int nb  = blockIdx.x * 32;

    const float4* W4  = (const float4*)W;
    float4*       Ws4 = (float4*)Ws;
#pragma unroll
    for (int i = 0; i < 4; ++i) Ws4[tid + i * 256] = W4[tid + i * 256];

#pragma unroll
    for (int i = 0; i < 4; ++i) {
        int idx  = tid + i * 256;
        int node = idx >> 5;
        int col4 = idx & 31;
        if (nb + node < N) {
            float4 v = ((const float4*)(x + (size_t)nb * 128))[idx];
            float* p = &xs[node * 129 + col4 * 4];
            p[0] = v.x; p[1] = v.y; p[2] = v.z; p[3] = v.w;
        }
    }
    __syncthreads();

    const int nl = tid >> 3;
    const int og = (tid & 7) * 4;
    float a0 = 0.f, a1 = 0.f, a2 = 0.f, a3 = 0.f;
#pragma unroll 8
    for (int k = 0; k < 128; ++k) {
        float xv = xs[nl * 129 + k];
        const float* wp = &Ws[k * 32 + og];
        a0 = fmaf(xv, wp[0], a0);
        a1 = fmaf(xv, wp[1], a1);
        a2 = fmaf(xv, wp[2], a2);
        a3 = fmaf(xv, wp[3], a3);
    }
    int node = nb + nl;
    if (node < N) {
        float* out = &h[(size_t)node * 32 + og];
        out[0] = a0; out[1] = a1; out[2] = a2; out[3] = a3;
    }
}

// Pull-mode conv1 aggregation, fused with self-loop + bias + relu.
// One wave per node: f = lane&31, half = lane>>5 splits the edge list.
__global__ __launch_bounds__(TPB) void gather32_kernel(const int* __restrict__ off,
                                                       const int2* __restrict__ epair,
                                                       const float* __restrict__ h1,
                                                       const float* __restrict__ dinv,
                                                       const float* __restrict__ b,
                                                       float* __restrict__ outrelu,
                                                       int N, int E) {
    int wave = (blockIdx.x * TPB + threadIdx.x) >> 6;
    int lane = threadIdx.x & 63;
    if (wave >= N) return;
    const int i    = wave;
    const int f    = lane & 31;
    const int half = lane >> 5;
    const int s0 = off[i];
    const int s1 = (i + 1 < N) ? off[i + 1] : E;

    float acc = 0.f;
    int j = s0 + half;
    for (; j + 2 < s1; j += 4) {           // 2-edge unroll per half
        int2 pa = epair[j];
        int2 pb = epair[j + 2];
        acc = fmaf(__int_as_float(pa.y), h1[(size_t)pa.x * 32 + f], acc);
        acc = fmaf(__int_as_float(pb.y), h1[(size_t)pb.x * 32 + f], acc);
    }
    if (j < s1) {
        int2 p = epair[j];
        acc = fmaf(__int_as_float(p.y), h1[(size_t)p.x * 32 + f], acc);
    }
    acc += __shfl_xor(acc, 32);            // combine the two halves

    float di = dinv[i];
    float v  = fmaf(h1[(size_t)i * 32 + f], di * di, acc) + b[f];
    v = fmaxf(v, 0.f);
    if (half == 0) outrelu[(size_t)i * 32 + f] = v;
}

// h2[N,16] = h[N,32] @ W2[32,16]; thread per (node, f)
__global__ __launch_bounds__(TPB) void gemm2_kernel(const float* __restrict__ h,
                                                    const float* __restrict__ W,
                                                    float* __restrict__ out, int N) {
    __shared__ float Ws[32 * 16];
    int tid = threadIdx.x;
    if (tid < 128) ((float4*)Ws)[tid] = ((const float4*)W)[tid];
    __syncthreads();
    int idx  = blockIdx.x * TPB + tid;
    int node = idx >> 4;
    int f    = idx & 15;
    if (node >= N) return;
    const float* hr = &h[(size_t)node * 32];
    float acc = 0.f;
#pragma unroll
    for (int k = 0; k < 32; ++k) acc = fmaf(hr[k], Ws[k * 16 + f], acc);
    out[(size_t)node * 16 + f] = acc;
}

// Pull-mode conv2 aggregation fused with the whole epilogue:
// x2 = gather + h2*invdeg + b2; x1f = x2.fc1_w + fc1_b; c = sigmoid(x1f);
// r = hrelu.fc2_w[0:32] + c*fc2_w[32] + fc2_b.  out[i]=r, out[N+i]=x1f.
// One wave per node: f = lane&15, q = lane>>4 (4-way edge split).
__global__ __launch_bounds__(TPB) void gather16_final_kernel(const int* __restrict__ off,
                                                             const int2* __restrict__ epair,
                                                             const float* __restrict__ h2,
                                                             const float* __restrict__ hrelu,
                                                             const float* __restrict__ dinv,
                                                             const float* __restrict__ b2,
                                                             const float* __restrict__ fc1_w,
                                                             const float* __restrict__ fc1_b,
                                                             const float* __restrict__ fc2_w,
                                                             const float* __restrict__ fc2_b,
                                                             float* __restrict__ out,
                                                             int N, int E) {
    int wave = (blockIdx.x * TPB + threadIdx.x) >> 6;
    int lane = threadIdx.x & 63;
    if (wave >= N) return;
    const int i = wave;
    const int f = lane & 15;
    const int q = lane >> 4;
    const int s0 = off[i];
    const int s1 = (i + 1 < N) ? off[i + 1] : E;

    float acc = 0.f;
    int j = s0 + q;
    for (; j + 4 < s1; j += 8) {           // 2-edge unroll per quarter
        int2 pa = epair[j];
        int2 pb = epair[j + 4];
        acc = fmaf(__int_as_float(pa.y), h2[(size_t)pa.x * 16 + f], acc);
        acc = fmaf(__int_as_float(pb.y), h2[(size_t)pb.x * 16 + f], acc);
    }
    if (j < s1) {
        int2 p = epair[j];
        acc = fmaf(__int_as_float(p.y), h2[(size_t)p.x * 16 + f], acc);
    }
    acc += __shfl_xor(acc, 16);
    acc += __shfl_xor(acc, 32);            // all lanes now have full edge sum

    float di  = dinv[i];
    float inv = di * di;
    float x2  = fmaf(h2[(size_t)i * 16 + f], inv, acc) + b2[f];

    float part = x2 * fc1_w[f];
    part += __shfl_xor(part, 1);
    part += __shfl_xor(part, 2);
    part += __shfl_xor(part, 4);
    part += __shfl_xor(part, 8);
    float x1f = part + fc1_b[0];
    float c   = 1.0f / (1.0f + expf(-x1f));

    float rp = (lane < 32) ? hrelu[(size_t)i * 32 + lane] * fc2_w[lane] : 0.f;
    rp += __shfl_xor(rp, 1);
    rp += __shfl_xor(rp, 2);
    rp += __shfl_xor(rp, 4);
    rp += __shfl_xor(rp, 8);
    rp += __shfl_xor(rp, 16);
    rp += __shfl_xor(rp, 32);
    float r = fmaf(c, fc2_w[32], fc2_b[0]) + rp;

    if (lane == 0) {
        out[i]     = r;
        out[N + i] = x1f;
    }
}

extern "C" void kernel_launch(void* const* d_in, const int* in_sizes, int n_in,
                              void* d_out, int out_size, void* d_ws, size_t ws_size,
                              hipStream_t stream) {
    const float* x     = (const float*)d_in[0];
    const int*   ei    = (const int*)d_in[1];
    const float* ew    = (const float*)d_in[2];
    const float* W1    = (const float*)d_in[3];
    const float* b1    = (const float*)d_in[4];
    const float* W2    = (const float*)d_in[5];
    const float* b2    = (const float*)d_in[6];
    const float* fc1_w = (const float*)d_in[7];
    const float* fc1_b = (const float*)d_in[8];
    const float* fc2_w = (const float*)d_in[9];
    const float* fc2_b = (const float*)d_in[10];

    const int N = in_sizes[0] / 128;
    const int E = in_sizes[2];
    const int* src = ei;
    const int* dst = ei + E;

    // workspace (floats): deg[N] | h1[32N] (reused as h2[16N]) | hrelu[32N]
    //                     | cnt[N] i | off[N] i | cur[N] i | epair[E] int2
    float* ws    = (float*)d_ws;
    float* deg   = ws;
    float* h1    = deg + N;
    float* hrelu = h1 + (size_t)32 * N;
    int*   cnt   = (int*)(hrelu + (size_t)32 * N);
    int*   off   = cnt + N;
    int*   cur   = off + N;
    int2*  epair = (int2*)(cur + N);
    float* h2    = h1;                 // reuse: h1 dead after gather32

    // Defensive: if the workspace can't hold the CSR, bail out (produces a
    // clean correctness failure instead of a GPU memory fault).
    size_t need = (size_t)(1 + 32 + 32 + 3) * N * 4 + (size_t)E * 8;
    if (ws_size < need) return;

    hipMemsetAsync(deg, 0, (size_t)N * sizeof(float), stream);
    hipMemsetAsync(cnt, 0, (size_t)N * sizeof(int), stream);

    hist_kernel<<<(E + TPB - 1) / TPB, TPB, 0, stream>>>(dst, ew, cnt, deg, E);
    gemm1_kernel<<<(N + 31) / 32, TPB, 0, stream>>>(x, W1, h1, N);
    scan_kernel<<<1, 1024, 0, stream>>>(cnt, off, cur, N);
    dinv_kernel<<<(N + TPB - 1) / TPB, TPB, 0, stream>>>(deg, N);
    reorder_kernel<<<(E + TPB - 1) / TPB, TPB, 0, stream>>>(src, dst, ew, deg, cur, epair, E);

    gather32_kernel<<<(N + 3) / 4, TPB, 0, stream>>>(off, epair, h1, deg, b1, hrelu, N, E);
    gemm2_kernel<<<((N * 16) + TPB - 1) / TPB, TPB, 0, stream>>>(hrelu, W2, h2, N);
    gather16_final_kernel<<<(N + 3) / 4, TPB, 0, stream>>>(
        off, epair, h2, hrelu, deg, b2, fc1_w, fc1_b, fc2_w, fc2_b, (float*)d_out, N, E);
}

// Round 3
// 588.578 us; speedup vs baseline: 1.4057x; 1.4004x over previous
//
#include <hip/hip_runtime.h>
#include <math.h>

// ---------------------------------------------------------------------------
// GCN: x[N,128] -> conv1(W1[128,32]) -> relu -> conv2(W2[32,16]) -> fc heads
// Outputs (concat): r[N], x1f[N]
//
// CSR-pull design, v2. Round-2 profile showed hist_kernel (6.4M scattered
// atomics, cnt+deg) = 288 us and reorder (3.2M scattered atomics-with-return)
// as the new bottleneck: scattered atomics run ~22 G/s vs 308 G/s coalesced.
// This version:
//   - rank_kernel: ONLY cnt atomics (3.2M), storing rank[e] (atomic order).
//   - deg: recomputed from CSR rows by segmented sum (no atomics), fused with
//     dinv and the g1 = dinv*h1 row scaling.
//   - place_kernel: pos = off[d]+rank[e], zero atomics.
//   - epair stores {src, w}; dinv factors applied via pre-scaled g1/g2 and a
//     single dinv[d] multiply in the gathers (identical math, new rounding).
// rank[E] overlays the h1 buffer (gemm1 runs after place), so the workspace
// footprint stays at 67N*4 + 8E = 52.4 MB.
// ---------------------------------------------------------------------------

#define TPB 256

// rank[e] = arrival index of edge e within its dst bucket; cnt[d] = degree
__global__ __launch_bounds__(TPB) void rank_kernel(const int* __restrict__ dst,
                                                   int* __restrict__ cnt,
                                                   int* __restrict__ rank, int E) {
    int e = blockIdx.x * TPB + threadIdx.x;
    if (e < E) rank[e] = atomicAdd(&cnt[dst[e]], 1);
}

// Exclusive prefix sum of cnt[N] -> off[N].
// Single block, 1024 threads, 4 elements/thread/chunk; shfl wave scan + LDS.
__global__ __launch_bounds__(1024) void scan_kernel(const int* __restrict__ cnt,
                                                    int* __restrict__ off, int N) {
    __shared__ int wsum[16];
    __shared__ int wpre[17];            // wpre[16] = chunk total
    const int tid  = threadIdx.x;
    const int lane = tid & 63;
    const int wid  = tid >> 6;
    int carry = 0;                      // uniform across threads

    for (int base = 0; base < N; base += 4096) {
        int i0 = base + tid * 4;
        int v0 = 0, v1 = 0, v2 = 0, v3 = 0;
        if (i0 + 3 < N) {
            int4 v = *(const int4*)(cnt + i0);
            v0 = v.x; v1 = v.y; v2 = v.z; v3 = v.w;
        } else if (i0 < N) {
            v0 = cnt[i0];
            if (i0 + 1 < N) v1 = cnt[i0 + 1];
            if (i0 + 2 < N) v2 = cnt[i0 + 2];
        }
        int s = v0 + v1 + v2 + v3;

        int incl = s;
#pragma unroll
        for (int d = 1; d < 64; d <<= 1) {
            int t = __shfl_up(incl, d);
            if (lane >= d) incl += t;
        }
        if (lane == 63) wsum[wid] = incl;
        __syncthreads();

        if (wid == 0 && lane < 16) {
            int ws = wsum[lane];
            int wi = ws;
#pragma unroll
            for (int d = 1; d < 16; d <<= 1) {
                int t = __shfl_up(wi, d);
                if (lane >= d) wi += t;
            }
            wpre[lane] = wi - ws;       // exclusive wave prefix
            if (lane == 15) wpre[16] = wi;
        }
        __syncthreads();

        int excl = carry + wpre[wid] + (incl - s);
        int o0 = excl;
        int o1 = o0 + v0;
        int o2 = o1 + v1;
        int o3 = o2 + v2;
        if (i0     < N) off[i0]     = o0;
        if (i0 + 1 < N) off[i0 + 1] = o1;
        if (i0 + 2 < N) off[i0 + 2] = o2;
        if (i0 + 3 < N) off[i0 + 3] = o3;

        carry += wpre[16];
        __syncthreads();
    }
}

// epair[off[d]+rank[e]] = {src, w}  -- no atomics
__global__ __launch_bounds__(TPB) void place_kernel(const int* __restrict__ src,
                                                    const int* __restrict__ dst,
                                                    const float* __restrict__ ew,
                                                    const int* __restrict__ rank,
                                                    const int* __restrict__ off,
                                                    int2* __restrict__ epair, int E) {
    int e = blockIdx.x * TPB + threadIdx.x;
    if (e >= E) return;
    int d = dst[e];
    int pos = off[d] + rank[e];
    int2 p;
    p.x = src[e];
    p.y = __float_as_int(ew[e]);
    epair[pos] = p;
}

// Per node (one wave): deg = sum of w over CSR row; dinv = 1/sqrt(deg+1);
// g1 row = h1 row * dinv (in place); store dinv.
__global__ __launch_bounds__(TPB) void degscale_kernel(const int* __restrict__ off,
                                                       const int2* __restrict__ epair,
                                                       float* __restrict__ h1,   // -> g1
                                                       float* __restrict__ dinv,
                                                       int N, int E) {
    int i = (blockIdx.x * TPB + threadIdx.x) >> 6;
    int lane = threadIdx.x & 63;
    if (i >= N) return;
    const int s0 = off[i];
    const int s1 = (i + 1 < N) ? off[i + 1] : E;

    float sum = 0.f;
    for (int j = s0 + lane; j < s1; j += 64) sum += __int_as_float(epair[j].y);
#pragma unroll
    for (int d = 1; d < 64; d <<= 1) sum += __shfl_xor(sum, d);

    float dv = 1.0f / sqrtf(sum + 1.0f);
    if (lane < 32) h1[(size_t)i * 32 + lane] *= dv;
    if (lane == 0) dinv[i] = dv;
}

// h[N,32] = x[N,128] @ W[128,32].  Block: 32 nodes, 256 threads.
__global__ __launch_bounds__(TPB) void gemm1_kernel(const float* __restrict__ x,
                                                    const float* __restrict__ W,
                                                    float* __restrict__ h, int N) {
    __shared__ float Ws[128 * 32];     // 16 KB
    __shared__ float xs[32 * 129];     // padded stride 129 to kill bank conflicts
    const int tid = threadIdx.x;
    const int nb  = blockIdx.x * 32;

    const float4* W4  = (const float4*)W;
    float4*       Ws4 = (float4*)Ws;
#pragma unroll
    for (int i = 0; i < 4; ++i) Ws4[tid + i * 256] = W4[tid + i * 256];

#pragma unroll
    for (int i = 0; i < 4; ++i) {
        int idx  = tid + i * 256;
        int node = idx >> 5;
        int col4 = idx & 31;
        if (nb + node < N) {
            float4 v = ((const float4*)(x + (size_t)nb * 128))[idx];
            float* p = &xs[node * 129 + col4 * 4];
            p[0] = v.x; p[1] = v.y; p[2] = v.z; p[3] = v.w;
        }
    }
    __syncthreads();

    const int nl = tid >> 3;
    const int og = (tid & 7) * 4;
    float a0 = 0.f, a1 = 0.f, a2 = 0.f, a3 = 0.f;
#pragma unroll 8
    for (int k = 0; k < 128; ++k) {
        float xv = xs[nl * 129 + k];
        const float* wp = &Ws[k * 32 + og];
        a0 = fmaf(xv, wp[0], a0);
        a1 = fmaf(xv, wp[1], a1);
        a2 = fmaf(xv, wp[2], a2);
        a3 = fmaf(xv, wp[3], a3);
    }
    int node = nb + nl;
    if (node < N) {
        float* out = &h[(size_t)node * 32 + og];
        out[0] = a0; out[1] = a1; out[2] = a2; out[3] = a3;
    }
}

// Pull-mode conv1: out = relu(dinv[i]*(sum_e w*g1[src] + g1[i]) + b)
// One wave per node: f = lane&31, half = lane>>5 splits the edge list.
__global__ __launch_bounds__(TPB) void gather32_kernel(const int* __restrict__ off,
                                                       const int2* __restrict__ epair,
                                                       const float* __restrict__ g1,
                                                       const float* __restrict__ dinv,
                                                       const float* __restrict__ b,
                                                       float* __restrict__ outrelu,
                                                       int N, int E) {
    int wave = (blockIdx.x * TPB + threadIdx.x) >> 6;
    int lane = threadIdx.x & 63;
    if (wave >= N) return;
    const int i    = wave;
    const int f    = lane & 31;
    const int half = lane >> 5;
    const int s0 = off[i];
    const int s1 = (i + 1 < N) ? off[i + 1] : E;

    float acc = 0.f;
    int j = s0 + half;
    for (; j + 2 < s1; j += 4) {           // 2-edge unroll per half
        int2 pa = epair[j];
        int2 pb = epair[j + 2];
        acc = fmaf(__int_as_float(pa.y), g1[(size_t)pa.x * 32 + f], acc);
        acc = fmaf(__int_as_float(pb.y), g1[(size_t)pb.x * 32 + f], acc);
    }
    if (j < s1) {
        int2 p = epair[j];
        acc = fmaf(__int_as_float(p.y), g1[(size_t)p.x * 32 + f], acc);
    }
    acc += __shfl_xor(acc, 32);            // combine the two halves

    float dv = dinv[i];
    float v  = dv * (acc + g1[(size_t)i * 32 + f]) + b[f];
    v = fmaxf(v, 0.f);
    if (half == 0) outrelu[(size_t)i * 32 + f] = v;
}

// g2[N,16] = (h[N,32] @ W2[32,16]) * dinv[node]; thread per (node, f)
__global__ __launch_bounds__(TPB) void gemm2_kernel(const float* __restrict__ h,
                                                    const float* __restrict__ W,
                                                    const float* __restrict__ dinv,
                                                    float* __restrict__ out, int N) {
    __shared__ float Ws[32 * 16];
    int tid = threadIdx.x;
    if (tid < 128) ((float4*)Ws)[tid] = ((const float4*)W)[tid];
    __syncthreads();
    int idx  = blockIdx.x * TPB + tid;
    int node = idx >> 4;
    int f    = idx & 15;
    if (node >= N) return;
    const float* hr = &h[(size_t)node * 32];
    float acc = 0.f;
#pragma unroll
    for (int k = 0; k < 32; ++k) acc = fmaf(hr[k], Ws[k * 16 + f], acc);
    out[(size_t)node * 16 + f] = acc * dinv[node];
}

// Pull-mode conv2 fused with the whole epilogue:
// x2 = dinv[i]*(sum_e w*g2[src] + g2[i]) + b2; x1f = x2.fc1_w + fc1_b;
// c = sigmoid(x1f); r = hrelu.fc2_w[0:32] + c*fc2_w[32] + fc2_b.
// One wave per node: f = lane&15, q = lane>>4 (4-way edge split).
__global__ __launch_bounds__(TPB) void gather16_final_kernel(const int* __restrict__ off,
                                                             const int2* __restrict__ epair,
                                                             const float* __restrict__ g2,
                                                             const float* __restrict__ hrelu,
                                                             const float* __restrict__ dinv,
                                                             const float* __restrict__ b2,
                                                             const float* __restrict__ fc1_w,
                                                             const float* __restrict__ fc1_b,
                                                             const float* __restrict__ fc2_w,
                                                             const float* __restrict__ fc2_b,
                                                             float* __restrict__ out,
                                                             int N, int E) {
    int wave = (blockIdx.x * TPB + threadIdx.x) >> 6;
    int lane = threadIdx.x & 63;
    if (wave >= N) return;
    const int i = wave;
    const int f = lane & 15;
    const int q = lane >> 4;
    const int s0 = off[i];
    const int s1 = (i + 1 < N) ? off[i + 1] : E;

    float acc = 0.f;
    int j = s0 + q;
    for (; j + 4 < s1; j += 8) {           // 2-edge unroll per quarter
        int2 pa = epair[j];
        int2 pb = epair[j + 4];
        acc = fmaf(__int_as_float(pa.y), g2[(size_t)pa.x * 16 + f], acc);
        acc = fmaf(__int_as_float(pb.y), g2[(size_t)pb.x * 16 + f], acc);
    }
    if (j < s1) {
        int2 p = epair[j];
        acc = fmaf(__int_as_float(p.y), g2[(size_t)p.x * 16 + f], acc);
    }
    acc += __shfl_xor(acc, 16);
    acc += __shfl_xor(acc, 32);            // all lanes now have full edge sum

    float dv = dinv[i];
    float x2 = dv * (acc + g2[(size_t)i * 16 + f]) + b2[f];

    float part = x2 * fc1_w[f];
    part += __shfl_xor(part, 1);
    part += __shfl_xor(part, 2);
    part += __shfl_xor(part, 4);
    part += __shfl_xor(part, 8);
    float x1f = part + fc1_b[0];
    float c   = 1.0f / (1.0f + expf(-x1f));

    float rp = (lane < 32) ? hrelu[(size_t)i * 32 + lane] * fc2_w[lane] : 0.f;
    rp += __shfl_xor(rp, 1);
    rp += __shfl_xor(rp, 2);
    rp += __shfl_xor(rp, 4);
    rp += __shfl_xor(rp, 8);
    rp += __shfl_xor(rp, 16);
    rp += __shfl_xor(rp, 32);
    float r = fmaf(c, fc2_w[32], fc2_b[0]) + rp;

    if (lane == 0) {
        out[i]     = r;
        out[N + i] = x1f;
    }
}

extern "C" void kernel_launch(void* const* d_in, const int* in_sizes, int n_in,
                              void* d_out, int out_size, void* d_ws, size_t ws_size,
                              hipStream_t stream) {
    const float* x     = (const float*)d_in[0];
    const int*   ei    = (const int*)d_in[1];
    const float* ew    = (const float*)d_in[2];
    const float* W1    = (const float*)d_in[3];
    const float* b1    = (const float*)d_in[4];
    const float* W2    = (const float*)d_in[5];
    const float* b2    = (const float*)d_in[6];
    const float* fc1_w = (const float*)d_in[7];
    const float* fc1_b = (const float*)d_in[8];
    const float* fc2_w = (const float*)d_in[9];
    const float* fc2_b = (const float*)d_in[10];

    const int N = in_sizes[0] / 128;
    const int E = in_sizes[2];
    const int* src = ei;
    const int* dst = ei + E;

    // workspace (floats): dinv[N] | h1[32N] (g1; also g2[16N] later; rank[E]
    // overlay during CSR build) | hrelu[32N] | cnt[N] i | off[N] i | epair[E] int2
    float* ws    = (float*)d_ws;
    float* dinv  = ws;
    float* h1    = dinv + N;
    float* hrelu = h1 + (size_t)32 * N;
    int*   cnt   = (int*)(hrelu + (size_t)32 * N);
    int*   off   = cnt + N;
    int2*  epair = (int2*)(off + N);
    float* g2    = h1;                 // reuse: g1 dead after gather32

    // rank[E] overlays h1 (32N floats) while h1 is not yet computed
    bool rank_fits = ((size_t)E <= (size_t)32 * N);
    int* rank = rank_fits ? (int*)h1 : (int*)(epair + E);

    size_t need = (size_t)(1 + 32 + 32 + 2) * N * 4 + (size_t)E * 8
                + (rank_fits ? 0 : (size_t)E * 4);
    if (ws_size < need) return;        // clean failure instead of mem fault

    hipMemsetAsync(cnt, 0, (size_t)N * sizeof(int), stream);

    rank_kernel<<<(E + TPB - 1) / TPB, TPB, 0, stream>>>(dst, cnt, rank, E);
    scan_kernel<<<1, 1024, 0, stream>>>(cnt, off, N);
    place_kernel<<<(E + TPB - 1) / TPB, TPB, 0, stream>>>(src, dst, ew, rank, off, epair, E);

    gemm1_kernel<<<(N + 31) / 32, TPB, 0, stream>>>(x, W1, h1, N);   // overwrites rank
    degscale_kernel<<<(N + 3) / 4, TPB, 0, stream>>>(off, epair, h1, dinv, N, E);

    gather32_kernel<<<(N + 3) / 4, TPB, 0, stream>>>(off, epair, h1, dinv, b1, hrelu, N, E);
    gemm2_kernel<<<((N * 16) + TPB - 1) / TPB, TPB, 0, stream>>>(hrelu, W2, dinv, g2, N);
    gather16_final_kernel<<<(N + 3) / 4, TPB, 0, stream>>>(
        off, epair, g2, hrelu, dinv, b2, fc1_w, fc1_b, fc2_w, fc2_b, (float*)d_out, N, E);
}

// Round 5
// 403.413 us; speedup vs baseline: 2.0510x; 1.4590x over previous
//
#include <hip/hip_runtime.h>
#include <math.h>

// ---------------------------------------------------------------------------
// GCN: x[N,128] -> conv1(W1[128,32]) -> relu -> conv2(W2[32,16]) -> fc heads
// Outputs (concat): r[N], x1f[N]
//
// CSR-pull design, v4. v3 crashed: partA reserved per-bucket ranges from a
// ZERO-based cursor, so all buckets collided at the bottom of tmp and the
// unwritten tail fed garbage src indices (up to 2^24) into the gathers ->
// OOB reads -> GPU fault. v4 is a proper 3-phase bucketed counting sort:
//   countA: per-block LDS histogram of dst>>8; one coalesced global atomic
//           per (block,bucket) -- ~306K atomics total.
//   kscan:  one-wave scan -> gstart[K+1]; gcursor[k] initialized to gstart[k].
//   placeA: LDS histogram + scan + absolute-range reservation from the based
//           cursor; LDS-staged reorder; stream out as mostly-sequential runs.
//   partB:  one block per bucket; 256-bin LDS histogram -> off[], weighted
//           degree -> dinv[], epair placement within a 65KB cached window.
// gemm1 applies dinv in its epilogue (g1 = dinv*h1). Gathers identical to the
// verified round-3 kernel. Workspace: (66N + 2E + 2K + 2)*4 = 52.0 MB.
// ---------------------------------------------------------------------------

#define TPB 256
#define PA_CHUNK 4096
#define KMAXB 512

// ---------------- phase 1: per-bucket edge counts --------------------------
__global__ __launch_bounds__(512) void countA_kernel(const int* __restrict__ dst,
                                                     int* __restrict__ gtot,
                                                     int E, int K) {
    __shared__ int lhist[KMAXB];
    const int tid = threadIdx.x;
    const int e0  = blockIdx.x * PA_CHUNK;
    if (tid < KMAXB) lhist[tid] = 0;
    __syncthreads();
#pragma unroll
    for (int i = 0; i < 8; ++i) {
        int e = e0 + tid + i * 512;
        if (e < E) atomicAdd(&lhist[dst[e] >> 8], 1);
    }
    __syncthreads();
    if (tid < K && lhist[tid] > 0) atomicAdd(&gtot[tid], lhist[tid]);
}

// ------- phase 2: scan totals -> gstart[K+1]; gcursor = gstart -------------
__global__ __launch_bounds__(64) void kscan_kernel(const int* __restrict__ gtot,
                                                   int* __restrict__ gstart,
                                                   int* __restrict__ gcursor,
                                                   int K, int E) {
    int tid = threadIdx.x;                  // one wave
    int b0 = tid * 8, v[8], s = 0;
#pragma unroll
    for (int t = 0; t < 8; ++t) {
        v[t] = s;
        int idx = b0 + t;
        s += (idx < K) ? gtot[idx] : 0;
    }
    int incl = s;
#pragma unroll
    for (int d = 1; d < 64; d <<= 1) {
        int t2 = __shfl_up(incl, d);
        if (tid >= d) incl += t2;
    }
    int excl = incl - s;
#pragma unroll
    for (int t = 0; t < 8; ++t) {
        int idx = b0 + t;
        if (idx < K) { gstart[idx] = excl + v[t]; gcursor[idx] = excl + v[t]; }
    }
    if (tid == 63) gstart[K] = E;
}

// ---------- phase 3: place edges into bucket-contiguous tmp ----------------
__global__ __launch_bounds__(512) void placeA_kernel(const int* __restrict__ src,
                                                     const int* __restrict__ dst,
                                                     const float* __restrict__ ew,
                                                     uint2* __restrict__ tmp,
                                                     int* __restrict__ gcursor,
                                                     int E, int K) {
    __shared__ int lhist[KMAXB], lbase[KMAXB], lcur[KMAXB], gbaseS[KMAXB];
    __shared__ int ltot;
    __shared__ uint2 stage[PA_CHUNK];
    __shared__ int   saddr[PA_CHUNK];
    const int tid = threadIdx.x;
    const int e0  = blockIdx.x * PA_CHUNK;

    if (tid < KMAXB) { lhist[tid] = 0; lcur[tid] = 0; }
    __syncthreads();

    int   b[8];
    uint2 p[8];
#pragma unroll
    for (int i = 0; i < 8; ++i) {
        int e = e0 + tid + i * 512;
        b[i] = -1;
        if (e < E) {
            int d   = dst[e];
            int s   = src[e];
            float w = ew[e];
            b[i]   = d >> 8;
            p[i].x = __float_as_uint(w);
            p[i].y = ((unsigned)s << 8) | (unsigned)(d & 255);
            atomicAdd(&lhist[b[i]], 1);
        }
    }
    __syncthreads();

    // exclusive scan lhist -> lbase (single wave, 8 bins/lane over 512)
    if (tid < 64) {
        int b0 = tid * 8, v[8], s = 0;
#pragma unroll
        for (int t = 0; t < 8; ++t) { v[t] = s; s += lhist[b0 + t]; }
        int incl = s;
#pragma unroll
        for (int d = 1; d < 64; d <<= 1) {
            int t2 = __shfl_up(incl, d);
            if (tid >= d) incl += t2;
        }
        int excl = incl - s;
#pragma unroll
        for (int t = 0; t < 8; ++t) lbase[b0 + t] = excl + v[t];
        if (tid == 63) ltot = incl;
    }
    __syncthreads();

    // reserve ABSOLUTE ranges from the based cursor (coalesced atomics)
    if (tid < K && lhist[tid] > 0)
        gbaseS[tid] = atomicAdd(&gcursor[tid], lhist[tid]);
    __syncthreads();

    // rank within (block,bucket), stage into LDS with absolute address
#pragma unroll
    for (int i = 0; i < 8; ++i) {
        if (b[i] >= 0) {
            int r    = atomicAdd(&lcur[b[i]], 1);
            int sidx = lbase[b[i]] + r;
            stage[sidx] = p[i];
            saddr[sidx] = gbaseS[b[i]] + r;
        }
    }
    __syncthreads();

    int tot = ltot;
    for (int s = tid; s < tot; s += 512) tmp[saddr[s]] = stage[s];
}

// -------- phase 4: per-bucket CSR (off, epair) + weighted deg -> dinv ------
__global__ __launch_bounds__(512) void partB_kernel(const uint2* __restrict__ tmp,
                                                    const int* __restrict__ gstart,
                                                    int2* __restrict__ epair,
                                                    int* __restrict__ off,
                                                    float* __restrict__ dinv,
                                                    int N) {
    __shared__ int   lhist[256], loff[256], lcur[256];
    __shared__ float ldeg[256];
    const int tid  = threadIdx.x;
    const int k    = blockIdx.x;
    const int seg0 = gstart[k], seg1 = gstart[k + 1];

    if (tid < 256) { lhist[tid] = 0; lcur[tid] = 0; ldeg[tid] = 0.f; }
    __syncthreads();

    for (int j = seg0 + tid; j < seg1; j += 512)
        atomicAdd(&lhist[tmp[j].y & 255u], 1);
    __syncthreads();

    if (tid < 64) {
        int b0 = tid * 4, v[4], s = 0;
#pragma unroll
        for (int t = 0; t < 4; ++t) { v[t] = s; s += lhist[b0 + t]; }
        int incl = s;
#pragma unroll
        for (int d = 1; d < 64; d <<= 1) {
            int t2 = __shfl_up(incl, d);
            if (tid >= d) incl += t2;
        }
        int excl = incl - s;
#pragma unroll
        for (int t = 0; t < 4; ++t) loff[b0 + t] = excl + v[t];
    }
    __syncthreads();

    if (tid < 256) {
        int d = (k << 8) + tid;
        if (d < N) off[d] = seg0 + loff[tid];
    }

    for (int j = seg0 + tid; j < seg1; j += 512) {
        uint2 q  = tmp[j];
        int dlow = q.y & 255u;
        int s    = (int)(q.y >> 8);
        float w  = __uint_as_float(q.x);
        int r    = atomicAdd(&lcur[dlow], 1);
        int2 pr; pr.x = s; pr.y = (int)q.x;
        epair[seg0 + loff[dlow] + r] = pr;   // scatter within 65KB window
        atomicAdd(&ldeg[dlow], w);
    }
    __syncthreads();

    if (tid < 256) {
        int d = (k << 8) + tid;
        if (d < N) dinv[d] = 1.0f / sqrtf(ldeg[tid] + 1.0f);
    }
}

// g1[N,32] = (x[N,128] @ W[128,32]) * dinv[node].  Block: 32 nodes.
__global__ __launch_bounds__(TPB) void gemm1_kernel(const float* __restrict__ x,
                                                    const float* __restrict__ W,
                                                    const float* __restrict__ dinv,
                                                    float* __restrict__ h, int N) {
    __shared__ float Ws[128 * 32];     // 16 KB
    __shared__ float xs[32 * 129];     // padded stride kills bank conflicts
    const int tid = threadIdx.x;
    const int nb  = blockIdx.x * 32;

    const float4* W4  = (const float4*)W;
    float4*       Ws4 = (float4*)Ws;
#pragma unroll
    for (int i = 0; i < 4; ++i) Ws4[tid + i * 256] = W4[tid + i * 256];

#pragma unroll
    for (int i = 0; i < 4; ++i) {
        int idx  = tid + i * 256;
        int node = idx >> 5;
        int col4 = idx & 31;
        if (nb + node < N) {
            float4 v = ((const float4*)(x + (size_t)nb * 128))[idx];
            float* p = &xs[node * 129 + col4 * 4];
            p[0] = v.x; p[1] = v.y; p[2] = v.z; p[3] = v.w;
        }
    }
    __syncthreads();

    const int nl = tid >> 3;
    const int og = (tid & 7) * 4;
    float a0 = 0.f, a1 = 0.f, a2 = 0.f, a3 = 0.f;
#pragma unroll 8
    for (int k = 0; k < 128; ++k) {
        float xv = xs[nl * 129 + k];
        const float* wp = &Ws[k * 32 + og];
        a0 = fmaf(xv, wp[0], a0);
        a1 = fmaf(xv, wp[1], a1);
        a2 = fmaf(xv, wp[2], a2);
        a3 = fmaf(xv, wp[3], a3);
    }
    int node = nb + nl;
    if (node < N) {
        float dv = dinv[node];
        float* out = &h[(size_t)node * 32 + og];
        out[0] = a0 * dv; out[1] = a1 * dv; out[2] = a2 * dv; out[3] = a3 * dv;
    }
}

// Pull-mode conv1: out = relu(dinv[i]*(sum_e w*g1[src] + g1[i]) + b)
__global__ __launch_bounds__(TPB) void gather32_kernel(const int* __restrict__ off,
                                                       const int2* __restrict__ epair,
                                                       const float* __restrict__ g1,
                                                       const float* __restrict__ dinv,
                                                       const float* __restrict__ b,
                                                       float* __restrict__ outrelu,
                                                       int N, int E) {
    int wave = (blockIdx.x * TPB + threadIdx.x) >> 6;
    int lane = threadIdx.x & 63;
    if (wave >= N) return;
    const int i    = wave;
    const int f    = lane & 31;
    const int half = lane >> 5;
    const int s0 = off[i];
    const int s1 = (i + 1 < N) ? off[i + 1] : E;

    float acc = 0.f;
    int j = s0 + half;
    for (; j + 2 < s1; j += 4) {
        int2 pa = epair[j];
        int2 pb = epair[j + 2];
        acc = fmaf(__int_as_float(pa.y), g1[(size_t)pa.x * 32 + f], acc);
        acc = fmaf(__int_as_float(pb.y), g1[(size_t)pb.x * 32 + f], acc);
    }
    if (j < s1) {
        int2 p = epair[j];
        acc = fmaf(__int_as_float(p.y), g1[(size_t)p.x * 32 + f], acc);
    }
    acc += __shfl_xor(acc, 32);

    float dv = dinv[i];
    float v  = dv * (acc + g1[(size_t)i * 32 + f]) + b[f];
    v = fmaxf(v, 0.f);
    if (half == 0) outrelu[(size_t)i * 32 + f] = v;
}

// g2[N,16] = (h[N,32] @ W2[32,16]) * dinv[node]
__global__ __launch_bounds__(TPB) void gemm2_kernel(const float* __restrict__ h,
                                                    const float* __restrict__ W,
                                                    const float* __restrict__ dinv,
                                                    float* __restrict__ out, int N) {
    __shared__ float Ws[32 * 16];
    int tid = threadIdx.x;
    if (tid < 128) ((float4*)Ws)[tid] = ((const float4*)W)[tid];
    __syncthreads();
    int idx  = blockIdx.x * TPB + tid;
    int node = idx >> 4;
    int f    = idx & 15;
    if (node >= N) return;
    const float* hr = &h[(size_t)node * 32];
    float acc = 0.f;
#pragma unroll
    for (int k = 0; k < 32; ++k) acc = fmaf(hr[k], Ws[k * 16 + f], acc);
    out[(size_t)node * 16 + f] = acc * dinv[node];
}

// Pull-mode conv2 fused with the whole epilogue.
__global__ __launch_bounds__(TPB) void gather16_final_kernel(const int* __restrict__ off,
                                                             const int2* __restrict__ epair,
                                                             const float* __restrict__ g2,
                                                             const float* __restrict__ hrelu,
                                                             const float* __restrict__ dinv,
                                                             const float* __restrict__ b2,
                                                             const float* __restrict__ fc1_w,
                                                             const float* __restrict__ fc1_b,
                                                             const float* __restrict__ fc2_w,
                                                             const float* __restrict__ fc2_b,
                                                             float* __restrict__ out,
                                                             int N, int E) {
    int wave = (blockIdx.x * TPB + threadIdx.x) >> 6;
    int lane = threadIdx.x & 63;
    if (wave >= N) return;
    const int i = wave;
    const int f = lane & 15;
    const int q = lane >> 4;
    const int s0 = off[i];
    const int s1 = (i + 1 < N) ? off[i + 1] : E;

    float acc = 0.f;
    int j = s0 + q;
    for (; j + 4 < s1; j += 8) {
        int2 pa = epair[j];
        int2 pb = epair[j + 4];
        acc = fmaf(__int_as_float(pa.y), g2[(size_t)pa.x * 16 + f], acc);
        acc = fmaf(__int_as_float(pb.y), g2[(size_t)pb.x * 16 + f], acc);
    }
    if (j < s1) {
        int2 p = epair[j];
        acc = fmaf(__int_as_float(p.y), g2[(size_t)p.x * 16 + f], acc);
    }
    acc += __shfl_xor(acc, 16);
    acc += __shfl_xor(acc, 32);

    float dv = dinv[i];
    float x2 = dv * (acc + g2[(size_t)i * 16 + f]) + b2[f];

    float part = x2 * fc1_w[f];
    part += __shfl_xor(part, 1);
    part += __shfl_xor(part, 2);
    part += __shfl_xor(part, 4);
    part += __shfl_xor(part, 8);
    float x1f = part + fc1_b[0];
    float c   = 1.0f / (1.0f + expf(-x1f));

    float rp = (lane < 32) ? hrelu[(size_t)i * 32 + lane] * fc2_w[lane] : 0.f;
    rp += __shfl_xor(rp, 1);
    rp += __shfl_xor(rp, 2);
    rp += __shfl_xor(rp, 4);
    rp += __shfl_xor(rp, 8);
    rp += __shfl_xor(rp, 16);
    rp += __shfl_xor(rp, 32);
    float r = fmaf(c, fc2_w[32], fc2_b[0]) + rp;

    if (lane == 0) {
        out[i]     = r;
        out[N + i] = x1f;
    }
}

extern "C" void kernel_launch(void* const* d_in, const int* in_sizes, int n_in,
                              void* d_out, int out_size, void* d_ws, size_t ws_size,
                              hipStream_t stream) {
    const float* x     = (const float*)d_in[0];
    const int*   ei    = (const int*)d_in[1];
    const float* ew    = (const float*)d_in[2];
    const float* W1    = (const float*)d_in[3];
    const float* b1    = (const float*)d_in[4];
    const float* W2    = (const float*)d_in[5];
    const float* b2    = (const float*)d_in[6];
    const float* fc1_w = (const float*)d_in[7];
    const float* fc1_b = (const float*)d_in[8];
    const float* fc2_w = (const float*)d_in[9];
    const float* fc2_b = (const float*)d_in[10];

    const int N = in_sizes[0] / 128;
    const int E = in_sizes[2];
    const int* src = ei;
    const int* dst = ei + E;
    const int K = (N + 255) >> 8;          // dst-buckets of 256 nodes

    // workspace (floats):
    //   dinv[N] | hreg[64N] (tmp overlay during build; later h1[32N]+hrelu[32N])
    //   | off[N] | epair[E] int2 | gcursor[K] | gstart[K+1]
    float* ws    = (float*)d_ws;
    float* dinv  = ws;
    float* hreg  = dinv + N;
    float* h1    = hreg;
    float* hrelu = hreg + (size_t)32 * N;
    int*   off   = (int*)(hreg + (size_t)64 * N);
    int2*  epair = (int2*)(off + N);
    int*   gcursor = (int*)(epair + E);
    int*   gstart  = gcursor + K;
    uint2* tmp   = (uint2*)hreg;           // E uint2 <= 64N floats (E <= 32N)
    float* g2    = h1;                     // reuse after gather32

    size_t need = ((size_t)66 * N + (size_t)2 * E + 2 * K + 2) * 4;
    if (ws_size < need || K > KMAXB || (size_t)E > (size_t)32 * N) return;

    hipMemsetAsync(gcursor, 0, (size_t)K * sizeof(int), stream);

    // counts accumulate into gcursor; kscan converts to bases (gstart+cursor)
    countA_kernel<<<(E + PA_CHUNK - 1) / PA_CHUNK, 512, 0, stream>>>(dst, gcursor, E, K);
    kscan_kernel<<<1, 64, 0, stream>>>(gcursor, gstart, gcursor, K, E);
    placeA_kernel<<<(E + PA_CHUNK - 1) / PA_CHUNK, 512, 0, stream>>>(
        src, dst, ew, tmp, gcursor, E, K);
    partB_kernel<<<K, 512, 0, stream>>>(tmp, gstart, epair, off, dinv, N);

    gemm1_kernel<<<(N + 31) / 32, TPB, 0, stream>>>(x, W1, dinv, h1, N);

    gather32_kernel<<<(N + 3) / 4, TPB, 0, stream>>>(off, epair, h1, dinv, b1, hrelu, N, E);
    gemm2_kernel<<<((N * 16) + TPB - 1) / TPB, TPB, 0, stream>>>(hrelu, W2, dinv, g2, N);
    gather16_final_kernel<<<(N + 3) / 4, TPB, 0, stream>>>(
        off, epair, g2, hrelu, dinv, b2, fc1_w, fc1_b, fc2_w, fc2_b, (float*)d_out, N, E);
}

// Round 6
// 383.994 us; speedup vs baseline: 2.1547x; 1.0506x over previous
//
#include <hip/hip_runtime.h>
#include <math.h>

// ---------------------------------------------------------------------------
// GCN: x[N,128] -> conv1(W1[128,32]) -> relu -> conv2(W2[32,16]) -> fc heads
// Outputs (concat): r[N], x1f[N]
//
// CSR-pull design, v5. Build pipeline (countA/kscan/placeA/partB) unchanged
// from the verified v4. Compute side restructured:
//   - gather32_fused: pull-gather conv1 + relu + (h2 = hrelu@W2)*dinv -> g2
//     AND rdot = hrelu . fc2_w[0:32] -> rdot[N], via a 32-step shfl matvec.
//     gemm2 kernel and the entire hrelu buffer are eliminated.
//   - both gathers: 4-deep unroll (4 independent epair->g row chains per
//     lane-group) to raise memory-level parallelism on the random fetches;
//     8 nodes per wave to amortize per-wave preloads.
// Workspace identical to v4: (66N + 2E + 2K + 2)*4 = 52.0 MB
//   dinv[N] | big[64N] = {tmp overlay} then {g1[32N] g2[16N] rdot[N] pad}
//   | off[N] | epair[E] int2 | gcursor[K] | gstart[K+1]
// ---------------------------------------------------------------------------

#define TPB 256
#define PA_CHUNK 4096
#define KMAXB 512
#define NPW 8              // nodes per wave in the gather kernels

// ---------------- phase 1: per-bucket edge counts --------------------------
__global__ __launch_bounds__(512) void countA_kernel(const int* __restrict__ dst,
                                                     int* __restrict__ gtot,
                                                     int E, int K) {
    __shared__ int lhist[KMAXB];
    const int tid = threadIdx.x;
    const int e0  = blockIdx.x * PA_CHUNK;
    if (tid < KMAXB) lhist[tid] = 0;
    __syncthreads();
#pragma unroll
    for (int i = 0; i < 8; ++i) {
        int e = e0 + tid + i * 512;
        if (e < E) atomicAdd(&lhist[dst[e] >> 8], 1);
    }
    __syncthreads();
    if (tid < K && lhist[tid] > 0) atomicAdd(&gtot[tid], lhist[tid]);
}

// ------- phase 2: scan totals -> gstart[K+1]; gcursor = gstart -------------
__global__ __launch_bounds__(64) void kscan_kernel(const int* __restrict__ gtot,
                                                   int* __restrict__ gstart,
                                                   int* __restrict__ gcursor,
                                                   int K, int E) {
    int tid = threadIdx.x;                  // one wave
    int b0 = tid * 8, v[8], s = 0;
#pragma unroll
    for (int t = 0; t < 8; ++t) {
        v[t] = s;
        int idx = b0 + t;
        s += (idx < K) ? gtot[idx] : 0;
    }
    int incl = s;
#pragma unroll
    for (int d = 1; d < 64; d <<= 1) {
        int t2 = __shfl_up(incl, d);
        if (tid >= d) incl += t2;
    }
    int excl = incl - s;
#pragma unroll
    for (int t = 0; t < 8; ++t) {
        int idx = b0 + t;
        if (idx < K) { gstart[idx] = excl + v[t]; gcursor[idx] = excl + v[t]; }
    }
    if (tid == 63) gstart[K] = E;
}

// ---------- phase 3: place edges into bucket-contiguous tmp ----------------
__global__ __launch_bounds__(512) void placeA_kernel(const int* __restrict__ src,
                                                     const int* __restrict__ dst,
                                                     const float* __restrict__ ew,
                                                     uint2* __restrict__ tmp,
                                                     int* __restrict__ gcursor,
                                                     int E, int K) {
    __shared__ int lhist[KMAXB], lbase[KMAXB], lcur[KMAXB], gbaseS[KMAXB];
    __shared__ int ltot;
    __shared__ uint2 stage[PA_CHUNK];
    __shared__ int   saddr[PA_CHUNK];
    const int tid = threadIdx.x;
    const int e0  = blockIdx.x * PA_CHUNK;

    if (tid < KMAXB) { lhist[tid] = 0; lcur[tid] = 0; }
    __syncthreads();

    int   b[8];
    uint2 p[8];
#pragma unroll
    for (int i = 0; i < 8; ++i) {
        int e = e0 + tid + i * 512;
        b[i] = -1;
        if (e < E) {
            int d   = dst[e];
            int s   = src[e];
            float w = ew[e];
            b[i]   = d >> 8;
            p[i].x = __float_as_uint(w);
            p[i].y = ((unsigned)s << 8) | (unsigned)(d & 255);
            atomicAdd(&lhist[b[i]], 1);
        }
    }
    __syncthreads();

    // exclusive scan lhist -> lbase (single wave, 8 bins/lane over 512)
    if (tid < 64) {
        int b0 = tid * 8, v[8], s = 0;
#pragma unroll
        for (int t = 0; t < 8; ++t) { v[t] = s; s += lhist[b0 + t]; }
        int incl = s;
#pragma unroll
        for (int d = 1; d < 64; d <<= 1) {
            int t2 = __shfl_up(incl, d);
            if (tid >= d) incl += t2;
        }
        int excl = incl - s;
#pragma unroll
        for (int t = 0; t < 8; ++t) lbase[b0 + t] = excl + v[t];
        if (tid == 63) ltot = incl;
    }
    __syncthreads();

    // reserve ABSOLUTE ranges from the based cursor (coalesced atomics)
    if (tid < K && lhist[tid] > 0)
        gbaseS[tid] = atomicAdd(&gcursor[tid], lhist[tid]);
    __syncthreads();

    // rank within (block,bucket), stage into LDS with absolute address
#pragma unroll
    for (int i = 0; i < 8; ++i) {
        if (b[i] >= 0) {
            int r    = atomicAdd(&lcur[b[i]], 1);
            int sidx = lbase[b[i]] + r;
            stage[sidx] = p[i];
            saddr[sidx] = gbaseS[b[i]] + r;
        }
    }
    __syncthreads();

    int tot = ltot;
    for (int s = tid; s < tot; s += 512) tmp[saddr[s]] = stage[s];
}

// -------- phase 4: per-bucket CSR (off, epair) + weighted deg -> dinv ------
__global__ __launch_bounds__(512) void partB_kernel(const uint2* __restrict__ tmp,
                                                    const int* __restrict__ gstart,
                                                    int2* __restrict__ epair,
                                                    int* __restrict__ off,
                                                    float* __restrict__ dinv,
                                                    int N) {
    __shared__ int   lhist[256], loff[256], lcur[256];
    __shared__ float ldeg[256];
    const int tid  = threadIdx.x;
    const int k    = blockIdx.x;
    const int seg0 = gstart[k], seg1 = gstart[k + 1];

    if (tid < 256) { lhist[tid] = 0; lcur[tid] = 0; ldeg[tid] = 0.f; }
    __syncthreads();

    for (int j = seg0 + tid; j < seg1; j += 512)
        atomicAdd(&lhist[tmp[j].y & 255u], 1);
    __syncthreads();

    if (tid < 64) {
        int b0 = tid * 4, v[4], s = 0;
#pragma unroll
        for (int t = 0; t < 4; ++t) { v[t] = s; s += lhist[b0 + t]; }
        int incl = s;
#pragma unroll
        for (int d = 1; d < 64; d <<= 1) {
            int t2 = __shfl_up(incl, d);
            if (tid >= d) incl += t2;
        }
        int excl = incl - s;
#pragma unroll
        for (int t = 0; t < 4; ++t) loff[b0 + t] = excl + v[t];
    }
    __syncthreads();

    if (tid < 256) {
        int d = (k << 8) + tid;
        if (d < N) off[d] = seg0 + loff[tid];
    }

    for (int j = seg0 + tid; j < seg1; j += 512) {
        uint2 q  = tmp[j];
        int dlow = q.y & 255u;
        int s    = (int)(q.y >> 8);
        float w  = __uint_as_float(q.x);
        int r    = atomicAdd(&lcur[dlow], 1);
        int2 pr; pr.x = s; pr.y = (int)q.x;
        epair[seg0 + loff[dlow] + r] = pr;   // scatter within 65KB window
        atomicAdd(&ldeg[dlow], w);
    }
    __syncthreads();

    if (tid < 256) {
        int d = (k << 8) + tid;
        if (d < N) dinv[d] = 1.0f / sqrtf(ldeg[tid] + 1.0f);
    }
}

// g1[N,32] = (x[N,128] @ W[128,32]) * dinv[node].  Block: 32 nodes.
__global__ __launch_bounds__(TPB) void gemm1_kernel(const float* __restrict__ x,
                                                    const float* __restrict__ W,
                                                    const float* __restrict__ dinv,
                                                    float* __restrict__ h, int N) {
    __shared__ float Ws[128 * 32];     // 16 KB
    __shared__ float xs[32 * 129];     // padded stride kills bank conflicts
    const int tid = threadIdx.x;
    const int nb  = blockIdx.x * 32;

    const float4* W4  = (const float4*)W;
    float4*       Ws4 = (float4*)Ws;
#pragma unroll
    for (int i = 0; i < 4; ++i) Ws4[tid + i * 256] = W4[tid + i * 256];

#pragma unroll
    for (int i = 0; i < 4; ++i) {
        int idx  = tid + i * 256;
        int node = idx >> 5;
        int col4 = idx & 31;
        if (nb + node < N) {
            float4 v = ((const float4*)(x + (size_t)nb * 128))[idx];
            float* p = &xs[node * 129 + col4 * 4];
            p[0] = v.x; p[1] = v.y; p[2] = v.z; p[3] = v.w;
        }
    }
    __syncthreads();

    const int nl = tid >> 3;
    const int og = (tid & 7) * 4;
    float a0 = 0.f, a1 = 0.f, a2 = 0.f, a3 = 0.f;
#pragma unroll 8
    for (int k = 0; k < 128; ++k) {
        float xv = xs[nl * 129 + k];
        const float* wp = &Ws[k * 32 + og];
        a0 = fmaf(xv, wp[0], a0);
        a1 = fmaf(xv, wp[1], a1);
        a2 = fmaf(xv, wp[2], a2);
        a3 = fmaf(xv, wp[3], a3);
    }
    int node = nb + nl;
    if (node < N) {
        float dv = dinv[node];
        float* out = &h[(size_t)node * 32 + og];
        out[0] = a0 * dv; out[1] = a1 * dv; out[2] = a2 * dv; out[3] = a3 * dv;
    }
}

// Pull-mode conv1 fused with relu, gemm2 (h2*dinv -> g2) and the fc2 dot
// (rdot = hrelu . fc2_w[0:32]). One wave handles NPW consecutive nodes.
// f = lane&31, half = lane>>5 splits the edge list; 4-deep unroll.
__global__ __launch_bounds__(TPB) void gather32_fused_kernel(
    const int* __restrict__ off, const int2* __restrict__ epair,
    const float* __restrict__ g1, const float* __restrict__ dinv,
    const float* __restrict__ b1, const float* __restrict__ W2,
    const float* __restrict__ fc2_w,
    float* __restrict__ g2, float* __restrict__ rdot, int N, int E) {
    __shared__ float wls[544];          // [0..511]=W2, [512..543]=fc2_w[0:32]
    const int tid = threadIdx.x;
    wls[tid]       = W2[tid];
    wls[tid + 256] = W2[tid + 256];
    if (tid < 32) wls[512 + tid] = fc2_w[tid];
    __syncthreads();

    const int lane = tid & 63;
    const int f    = lane & 31;
    const int half = lane >> 5;
    const float bv = b1[f];
    const int wbase = (lane < 16) ? lane : 512;   // W2 column | fc2_w
    const int wstrd = (lane < 16) ? 16 : 1;

    const int i0 = (blockIdx.x * (TPB / 64) + (tid >> 6)) * NPW;

    for (int t = 0; t < NPW; ++t) {
        int i = i0 + t;
        if (i >= N) return;
        const int s0 = off[i];
        const int s1 = (i + 1 < N) ? off[i + 1] : E;

        float acc = 0.f;
        int j = s0 + half;
        for (; j + 6 < s1; j += 8) {           // 4-edge unroll per half
            int2 pa = epair[j];
            int2 pb = epair[j + 2];
            int2 pc = epair[j + 4];
            int2 pd = epair[j + 6];
            acc = fmaf(__int_as_float(pa.y), g1[(size_t)pa.x * 32 + f], acc);
            acc = fmaf(__int_as_float(pb.y), g1[(size_t)pb.x * 32 + f], acc);
            acc = fmaf(__int_as_float(pc.y), g1[(size_t)pc.x * 32 + f], acc);
            acc = fmaf(__int_as_float(pd.y), g1[(size_t)pd.x * 32 + f], acc);
        }
        for (; j < s1; j += 2) {
            int2 p = epair[j];
            acc = fmaf(__int_as_float(p.y), g1[(size_t)p.x * 32 + f], acc);
        }
        acc += __shfl_xor(acc, 32);            // combine the two halves

        float dv = dinv[i];
        float v  = fmaxf(dv * (acc + g1[(size_t)i * 32 + f]) + bv, 0.f);

        // 32-step shfl matvec: lanes 0-15 -> h2[f2]; lanes >=16 -> rdot
        float hs = 0.f;
#pragma unroll
        for (int k = 0; k < 32; ++k)
            hs = fmaf(__shfl(v, k), wls[wbase + k * wstrd], hs);

        if (lane < 16)       g2[(size_t)i * 16 + lane] = hs * dv;
        else if (lane == 16) rdot[i] = hs;
    }
}

// Pull-mode conv2 fused with the epilogue:
// x2 = dinv*(edge-sum + g2[i]) + b2; x1f = x2.fc1_w + fc1_b; c = sigmoid;
// r = rdot[i] + c*fc2_w[32] + fc2_b.  f = lane&15, q = lane>>4; 4-deep unroll.
__global__ __launch_bounds__(TPB) void gather16_final_kernel(
    const int* __restrict__ off, const int2* __restrict__ epair,
    const float* __restrict__ g2, const float* __restrict__ rdot,
    const float* __restrict__ dinv, const float* __restrict__ b2,
    const float* __restrict__ fc1_w, const float* __restrict__ fc1_b,
    const float* __restrict__ fc2_w, const float* __restrict__ fc2_b,
    float* __restrict__ out, int N, int E) {
    const int tid  = threadIdx.x;
    const int lane = tid & 63;
    const int f    = lane & 15;
    const int q    = lane >> 4;
    const float b2v = b2[f];
    const float f1v = fc1_w[f];
    const float f1b = fc1_b[0];
    const float f2w = fc2_w[32];
    const float f2b = fc2_b[0];

    const int i0 = (blockIdx.x * (TPB / 64) + (tid >> 6)) * NPW;

    for (int t = 0; t < NPW; ++t) {
        int i = i0 + t;
        if (i >= N) return;
        const int s0 = off[i];
        const int s1 = (i + 1 < N) ? off[i + 1] : E;

        float acc = 0.f;
        int j = s0 + q;
        for (; j + 12 < s1; j += 16) {         // 4-edge unroll per quarter
            int2 pa = epair[j];
            int2 pb = epair[j + 4];
            int2 pc = epair[j + 8];
            int2 pd = epair[j + 12];
            acc = fmaf(__int_as_float(pa.y), g2[(size_t)pa.x * 16 + f], acc);
            acc = fmaf(__int_as_float(pb.y), g2[(size_t)pb.x * 16 + f], acc);
            acc = fmaf(__int_as_float(pc.y), g2[(size_t)pc.x * 16 + f], acc);
            acc = fmaf(__int_as_float(pd.y), g2[(size_t)pd.x * 16 + f], acc);
        }
        for (; j < s1; j += 4) {
            int2 p = epair[j];
            acc = fmaf(__int_as_float(p.y), g2[(size_t)p.x * 16 + f], acc);
        }
        acc += __shfl_xor(acc, 16);
        acc += __shfl_xor(acc, 32);            // full edge sum in all lanes

        float dv = dinv[i];
        float x2 = dv * (acc + g2[(size_t)i * 16 + f]) + b2v;

        float part = x2 * f1v;
        part += __shfl_xor(part, 1);
        part += __shfl_xor(part, 2);
        part += __shfl_xor(part, 4);
        part += __shfl_xor(part, 8);
        float x1f = part + f1b;
        float c   = 1.0f / (1.0f + expf(-x1f));
        float r   = fmaf(c, f2w, f2b) + rdot[i];

        if (lane == 0) {
            out[i]     = r;
            out[N + i] = x1f;
        }
    }
}

extern "C" void kernel_launch(void* const* d_in, const int* in_sizes, int n_in,
                              void* d_out, int out_size, void* d_ws, size_t ws_size,
                              hipStream_t stream) {
    const float* x     = (const float*)d_in[0];
    const int*   ei    = (const int*)d_in[1];
    const float* ew    = (const float*)d_in[2];
    const float* W1    = (const float*)d_in[3];
    const float* b1    = (const float*)d_in[4];
    const float* W2    = (const float*)d_in[5];
    const float* b2    = (const float*)d_in[6];
    const float* fc1_w = (const float*)d_in[7];
    const float* fc1_b = (const float*)d_in[8];
    const float* fc2_w = (const float*)d_in[9];
    const float* fc2_b = (const float*)d_in[10];

    const int N = in_sizes[0] / 128;
    const int E = in_sizes[2];
    const int* src = ei;
    const int* dst = ei + E;
    const int K = (N + 255) >> 8;          // dst-buckets of 256 nodes

    // workspace (floats):
    //   dinv[N] | big[64N] (tmp overlay during build; later g1|g2|rdot)
    //   | off[N] | epair[E] int2 | gcursor[K] | gstart[K+1]
    float* ws    = (float*)d_ws;
    float* dinv  = ws;
    float* big   = dinv + N;
    float* g1    = big;                            // 32N
    float* g2    = big + (size_t)32 * N;           // 16N
    float* rdot  = big + (size_t)48 * N;           // N
    int*   off   = (int*)(big + (size_t)64 * N);
    int2*  epair = (int2*)(off + N);
    int*   gcursor = (int*)(epair + E);
    int*   gstart  = gcursor + K;
    uint2* tmp   = (uint2*)big;                    // E uint2 <= 64N floats

    size_t need = ((size_t)66 * N + (size_t)2 * E + 2 * K + 2) * 4;
    if (ws_size < need || K > KMAXB || (size_t)E > (size_t)32 * N) return;

    hipMemsetAsync(gcursor, 0, (size_t)K * sizeof(int), stream);

    countA_kernel<<<(E + PA_CHUNK - 1) / PA_CHUNK, 512, 0, stream>>>(dst, gcursor, E, K);
    kscan_kernel<<<1, 64, 0, stream>>>(gcursor, gstart, gcursor, K, E);
    placeA_kernel<<<(E + PA_CHUNK - 1) / PA_CHUNK, 512, 0, stream>>>(
        src, dst, ew, tmp, gcursor, E, K);
    partB_kernel<<<K, 512, 0, stream>>>(tmp, gstart, epair, off, dinv, N);

    gemm1_kernel<<<(N + 31) / 32, TPB, 0, stream>>>(x, W1, dinv, g1, N);

    const int gblocks = (N + 4 * NPW - 1) / (4 * NPW);   // 4 waves x NPW nodes
    gather32_fused_kernel<<<gblocks, TPB, 0, stream>>>(
        off, epair, g1, dinv, b1, W2, fc2_w, g2, rdot, N, E);
    gather16_final_kernel<<<gblocks, TPB, 0, stream>>>(
        off, epair, g2, rdot, dinv, b2, fc1_w, fc1_b, fc2_w, fc2_b,
        (float*)d_out, N, E);
}

// Round 9
// 345.080 us; speedup vs baseline: 2.3977x; 1.1128x over previous
//
#include <hip/hip_runtime.h>
#include <math.h>

// ---------------------------------------------------------------------------
// GCN: x[N,128] -> conv1(W1[128,32]) -> relu -> conv2(W2[32,16]) -> fc heads
// Outputs (concat): r[N], x1f[N]
//
// CSR-pull v7 (hedged). v6 failed twice at container level with no profile;
// static audit found no defect, but this round de-risks: everything below is
// the VERIFIED v5 kernel (384 us) except two small additions:
//   - zprep: z[i] = g2[i,:] . fc1_w   (N dot-16s; g2 already carries dinv)
//   - final_scalar: conv2 collapses to a scalar gather because x2 is never
//     output:  x1f[i] = dinv[i]*(sum_e w*z[src] + z[i]) + (b2.fc1_w + fc1_b)
//     r = rdot[i] + sigmoid(x1f)*fc2_w[32] + fc2_b.
//     Replaces the 16-wide gather16_final (64 B/edge -> 12 B/edge, z is
//     0.4 MB = L2-resident on every XCD).
// Workspace: (66N + 2E + 2K + 2)*4 = 52.0 MB (z at big+49N, within 64N).
// ---------------------------------------------------------------------------

#define TPB 256
#define PA_CHUNK 4096
#define KMAXB 512
#define NPW 8              // nodes per wave in the gather kernels

// ---------------- phase 1: per-bucket edge counts --------------------------
__global__ __launch_bounds__(512) void countA_kernel(const int* __restrict__ dst,
                                                     int* __restrict__ gtot,
                                                     int E, int K) {
    __shared__ int lhist[KMAXB];
    const int tid = threadIdx.x;
    const int e0  = blockIdx.x * PA_CHUNK;
    if (tid < KMAXB) lhist[tid] = 0;
    __syncthreads();
#pragma unroll
    for (int i = 0; i < 8; ++i) {
        int e = e0 + tid + i * 512;
        if (e < E) atomicAdd(&lhist[dst[e] >> 8], 1);
    }
    __syncthreads();
    if (tid < K && lhist[tid] > 0) atomicAdd(&gtot[tid], lhist[tid]);
}

// ------- phase 2: scan totals -> gstart[K+1]; gcursor = gstart -------------
__global__ __launch_bounds__(64) void kscan_kernel(const int* __restrict__ gtot,
                                                   int* __restrict__ gstart,
                                                   int* __restrict__ gcursor,
                                                   int K, int E) {
    int tid = threadIdx.x;                  // one wave
    int b0 = tid * 8, v[8], s = 0;
#pragma unroll
    for (int t = 0; t < 8; ++t) {
        v[t] = s;
        int idx = b0 + t;
        s += (idx < K) ? gtot[idx] : 0;
    }
    int incl = s;
#pragma unroll
    for (int d = 1; d < 64; d <<= 1) {
        int t2 = __shfl_up(incl, d);
        if (tid >= d) incl += t2;
    }
    int excl = incl - s;
#pragma unroll
    for (int t = 0; t < 8; ++t) {
        int idx = b0 + t;
        if (idx < K) { gstart[idx] = excl + v[t]; gcursor[idx] = excl + v[t]; }
    }
    if (tid == 63) gstart[K] = E;
}

// ---------- phase 3: place edges into bucket-contiguous tmp ----------------
__global__ __launch_bounds__(512) void placeA_kernel(const int* __restrict__ src,
                                                     const int* __restrict__ dst,
                                                     const float* __restrict__ ew,
                                                     uint2* __restrict__ tmp,
                                                     int* __restrict__ gcursor,
                                                     int E, int K) {
    __shared__ int lhist[KMAXB], lbase[KMAXB], lcur[KMAXB], gbaseS[KMAXB];
    __shared__ int ltot;
    __shared__ uint2 stage[PA_CHUNK];
    __shared__ int   saddr[PA_CHUNK];
    const int tid = threadIdx.x;
    const int e0  = blockIdx.x * PA_CHUNK;

    if (tid < KMAXB) { lhist[tid] = 0; lcur[tid] = 0; }
    __syncthreads();

    int   b[8];
    uint2 p[8];
#pragma unroll
    for (int i = 0; i < 8; ++i) {
        int e = e0 + tid + i * 512;
        b[i] = -1;
        if (e < E) {
            int d   = dst[e];
            int s   = src[e];
            float w = ew[e];
            b[i]   = d >> 8;
            p[i].x = __float_as_uint(w);
            p[i].y = ((unsigned)s << 8) | (unsigned)(d & 255);
            atomicAdd(&lhist[b[i]], 1);
        }
    }
    __syncthreads();

    // exclusive scan lhist -> lbase (single wave, 8 bins/lane over 512)
    if (tid < 64) {
        int b0 = tid * 8, v[8], s = 0;
#pragma unroll
        for (int t = 0; t < 8; ++t) { v[t] = s; s += lhist[b0 + t]; }
        int incl = s;
#pragma unroll
        for (int d = 1; d < 64; d <<= 1) {
            int t2 = __shfl_up(incl, d);
            if (tid >= d) incl += t2;
        }
        int excl = incl - s;
#pragma unroll
        for (int t = 0; t < 8; ++t) lbase[b0 + t] = excl + v[t];
        if (tid == 63) ltot = incl;
    }
    __syncthreads();

    // reserve ABSOLUTE ranges from the based cursor (coalesced atomics)
    if (tid < K && lhist[tid] > 0)
        gbaseS[tid] = atomicAdd(&gcursor[tid], lhist[tid]);
    __syncthreads();

    // rank within (block,bucket), stage into LDS with absolute address
#pragma unroll
    for (int i = 0; i < 8; ++i) {
        if (b[i] >= 0) {
            int r    = atomicAdd(&lcur[b[i]], 1);
            int sidx = lbase[b[i]] + r;
            stage[sidx] = p[i];
            saddr[sidx] = gbaseS[b[i]] + r;
        }
    }
    __syncthreads();

    int tot = ltot;
    for (int s = tid; s < tot; s += 512) tmp[saddr[s]] = stage[s];
}

// -------- phase 4: per-bucket CSR (off, epair) + weighted deg -> dinv ------
__global__ __launch_bounds__(512) void partB_kernel(const uint2* __restrict__ tmp,
                                                    const int* __restrict__ gstart,
                                                    int2* __restrict__ epair,
                                                    int* __restrict__ off,
                                                    float* __restrict__ dinv,
                                                    int N) {
    __shared__ int   lhist[256], loff[256], lcur[256];
    __shared__ float ldeg[256];
    const int tid  = threadIdx.x;
    const int k    = blockIdx.x;
    const int seg0 = gstart[k], seg1 = gstart[k + 1];

    if (tid < 256) { lhist[tid] = 0; lcur[tid] = 0; ldeg[tid] = 0.f; }
    __syncthreads();

    for (int j = seg0 + tid; j < seg1; j += 512)
        atomicAdd(&lhist[tmp[j].y & 255u], 1);
    __syncthreads();

    if (tid < 64) {
        int b0 = tid * 4, v[4], s = 0;
#pragma unroll
        for (int t = 0; t < 4; ++t) { v[t] = s; s += lhist[b0 + t]; }
        int incl = s;
#pragma unroll
        for (int d = 1; d < 64; d <<= 1) {
            int t2 = __shfl_up(incl, d);
            if (tid >= d) incl += t2;
        }
        int excl = incl - s;
#pragma unroll
        for (int t = 0; t < 4; ++t) loff[b0 + t] = excl + v[t];
    }
    __syncthreads();

    if (tid < 256) {
        int d = (k << 8) + tid;
        if (d < N) off[d] = seg0 + loff[tid];
    }

    for (int j = seg0 + tid; j < seg1; j += 512) {
        uint2 q  = tmp[j];
        int dlow = q.y & 255u;
        int s    = (int)(q.y >> 8);
        float w  = __uint_as_float(q.x);
        int r    = atomicAdd(&lcur[dlow], 1);
        int2 pr; pr.x = s; pr.y = (int)q.x;
        epair[seg0 + loff[dlow] + r] = pr;   // scatter within 65KB window
        atomicAdd(&ldeg[dlow], w);
    }
    __syncthreads();

    if (tid < 256) {
        int d = (k << 8) + tid;
        if (d < N) dinv[d] = 1.0f / sqrtf(ldeg[tid] + 1.0f);
    }
}

// g1[N,32] = (x[N,128] @ W[128,32]) * dinv[node].  Block: 32 nodes.
__global__ __launch_bounds__(TPB) void gemm1_kernel(const float* __restrict__ x,
                                                    const float* __restrict__ W,
                                                    const float* __restrict__ dinv,
                                                    float* __restrict__ h, int N) {
    __shared__ float Ws[128 * 32];     // 16 KB
    __shared__ float xs[32 * 129];     // padded stride kills bank conflicts
    const int tid = threadIdx.x;
    const int nb  = blockIdx.x * 32;

    const float4* W4  = (const float4*)W;
    float4*       Ws4 = (float4*)Ws;
#pragma unroll
    for (int i = 0; i < 4; ++i) Ws4[tid + i * 256] = W4[tid + i * 256];

#pragma unroll
    for (int i = 0; i < 4; ++i) {
        int idx  = tid + i * 256;
        int node = idx >> 5;
        int col4 = idx & 31;
        if (nb + node < N) {
            float4 v = ((const float4*)(x + (size_t)nb * 128))[idx];
            float* p = &xs[node * 129 + col4 * 4];
            p[0] = v.x; p[1] = v.y; p[2] = v.z; p[3] = v.w;
        }
    }
    __syncthreads();

    const int nl = tid >> 3;
    const int og = (tid & 7) * 4;
    float a0 = 0.f, a1 = 0.f, a2 = 0.f, a3 = 0.f;
#pragma unroll 8
    for (int k = 0; k < 128; ++k) {
        float xv = xs[nl * 129 + k];
        const float* wp = &Ws[k * 32 + og];
        a0 = fmaf(xv, wp[0], a0);
        a1 = fmaf(xv, wp[1], a1);
        a2 = fmaf(xv, wp[2], a2);
        a3 = fmaf(xv, wp[3], a3);
    }
    int node = nb + nl;
    if (node < N) {
        float dv = dinv[node];
        float* out = &h[(size_t)node * 32 + og];
        out[0] = a0 * dv; out[1] = a1 * dv; out[2] = a2 * dv; out[3] = a3 * dv;
    }
}

// Pull-mode conv1 fused with relu, gemm2 (h2*dinv -> g2) and the fc2 dot
// (rdot = hrelu . fc2_w[0:32]). One wave handles NPW consecutive nodes.
// f = lane&31, half = lane>>5 splits the edge list; 4-deep unroll.
// (VERBATIM from the verified v5 kernel.)
__global__ __launch_bounds__(TPB) void gather32_fused_kernel(
    const int* __restrict__ off, const int2* __restrict__ epair,
    const float* __restrict__ g1, const float* __restrict__ dinv,
    const float* __restrict__ b1, const float* __restrict__ W2,
    const float* __restrict__ fc2_w,
    float* __restrict__ g2, float* __restrict__ rdot, int N, int E) {
    __shared__ float wls[544];          // [0..511]=W2, [512..543]=fc2_w[0:32]
    const int tid = threadIdx.x;
    wls[tid]       = W2[tid];
    wls[tid + 256] = W2[tid + 256];
    if (tid < 32) wls[512 + tid] = fc2_w[tid];
    __syncthreads();

    const int lane = tid & 63;
    const int f    = lane & 31;
    const int half = lane >> 5;
    const float bv = b1[f];
    const int wbase = (lane < 16) ? lane : 512;   // W2 column | fc2_w
    const int wstrd = (lane < 16) ? 16 : 1;

    const int i0 = (blockIdx.x * (TPB / 64) + (tid >> 6)) * NPW;

    for (int t = 0; t < NPW; ++t) {
        int i = i0 + t;
        if (i >= N) return;
        const int s0 = off[i];
        const int s1 = (i + 1 < N) ? off[i + 1] : E;

        float acc = 0.f;
        int j = s0 + half;
        for (; j + 6 < s1; j += 8) {           // 4-edge unroll per half
            int2 pa = epair[j];
            int2 pb = epair[j + 2];
            int2 pc = epair[j + 4];
            int2 pd = epair[j + 6];
            acc = fmaf(__int_as_float(pa.y), g1[(size_t)pa.x * 32 + f], acc);
            acc = fmaf(__int_as_float(pb.y), g1[(size_t)pb.x * 32 + f], acc);
            acc = fmaf(__int_as_float(pc.y), g1[(size_t)pc.x * 32 + f], acc);
            acc = fmaf(__int_as_float(pd.y), g1[(size_t)pd.x * 32 + f], acc);
        }
        for (; j < s1; j += 2) {
            int2 p = epair[j];
            acc = fmaf(__int_as_float(p.y), g1[(size_t)p.x * 32 + f], acc);
        }
        acc += __shfl_xor(acc, 32);            // combine the two halves

        float dv = dinv[i];
        float v  = fmaxf(dv * (acc + g1[(size_t)i * 32 + f]) + bv, 0.f);

        // 32-step shfl matvec: lanes 0-15 -> h2[f2]; lanes >=16 -> rdot
        float hs = 0.f;
#pragma unroll
        for (int k = 0; k < 32; ++k)
            hs = fmaf(__shfl(v, k), wls[wbase + k * wstrd], hs);

        if (lane < 16)       g2[(size_t)i * 16 + lane] = hs * dv;
        else if (lane == 16) rdot[i] = hs;
    }
}

// z[i] = g2[i,:] . fc1_w   (g2 already carries the dinv[i] factor)
__global__ __launch_bounds__(TPB) void zprep_kernel(const float* __restrict__ g2,
                                                    const float* __restrict__ fc1_w,
                                                    float* __restrict__ z, int N) {
    int i = blockIdx.x * TPB + threadIdx.x;
    if (i >= N) return;
    const float4* g4 = (const float4*)(g2 + (size_t)i * 16);
    float acc = 0.f;
#pragma unroll
    for (int q = 0; q < 4; ++q) {
        float4 v = g4[q];
        acc = fmaf(v.x, fc1_w[q * 4 + 0], acc);
        acc = fmaf(v.y, fc1_w[q * 4 + 1], acc);
        acc = fmaf(v.z, fc1_w[q * 4 + 2], acc);
        acc = fmaf(v.w, fc1_w[q * 4 + 3], acc);
    }
    z[i] = acc;
}

// Scalar conv2 aggregation + full epilogue:
//   x1f = dinv*(sum_e w*z[src] + z[i]) + (b2.fc1_w + fc1_b)
//   c = sigmoid(x1f);  r = rdot[i] + c*fc2_w[32] + fc2_b
// One wave per NPW nodes; 64 lanes stride each node's edge list.
__global__ __launch_bounds__(TPB) void final_scalar_kernel(
    const int* __restrict__ off, const int2* __restrict__ epair,
    const float* __restrict__ z, const float* __restrict__ rdot,
    const float* __restrict__ dinv, const float* __restrict__ b2,
    const float* __restrict__ fc1_w, const float* __restrict__ fc1_b,
    const float* __restrict__ fc2_w, const float* __restrict__ fc2_b,
    float* __restrict__ out, int N, int E) {
    const int tid  = threadIdx.x;
    const int lane = tid & 63;

    float C = fc1_b[0];
#pragma unroll
    for (int f = 0; f < 16; ++f) C = fmaf(b2[f], fc1_w[f], C);
    const float f2w = fc2_w[32];
    const float f2b = fc2_b[0];

    const int i0 = (blockIdx.x * (TPB / 64) + (tid >> 6)) * NPW;

    for (int t = 0; t < NPW; ++t) {
        int i = i0 + t;
        if (i >= N) return;
        const int s0 = off[i];
        const int s1 = (i + 1 < N) ? off[i + 1] : E;

        float acc = 0.f;
        for (int j = s0 + lane; j < s1; j += 64) {
            int2 p = epair[j];
            acc = fmaf(__int_as_float(p.y), z[p.x], acc);
        }
        acc += __shfl_xor(acc, 1);
        acc += __shfl_xor(acc, 2);
        acc += __shfl_xor(acc, 4);
        acc += __shfl_xor(acc, 8);
        acc += __shfl_xor(acc, 16);
        acc += __shfl_xor(acc, 32);

        float x1f = dinv[i] * (acc + z[i]) + C;
        float c   = 1.0f / (1.0f + expf(-x1f));
        float r   = fmaf(c, f2w, f2b) + rdot[i];

        if (lane == 0) {
            out[i]     = r;
            out[N + i] = x1f;
        }
    }
}

extern "C" void kernel_launch(void* const* d_in, const int* in_sizes, int n_in,
                              void* d_out, int out_size, void* d_ws, size_t ws_size,
                              hipStream_t stream) {
    const float* x     = (const float*)d_in[0];
    const int*   ei    = (const int*)d_in[1];
    const float* ew    = (const float*)d_in[2];
    const float* W1    = (const float*)d_in[3];
    const float* b1    = (const float*)d_in[4];
    const float* W2    = (const float*)d_in[5];
    const float* b2    = (const float*)d_in[6];
    const float* fc1_w = (const float*)d_in[7];
    const float* fc1_b = (const float*)d_in[8];
    const float* fc2_w = (const float*)d_in[9];
    const float* fc2_b = (const float*)d_in[10];

    const int N = in_sizes[0] / 128;
    const int E = in_sizes[2];
    const int* src = ei;
    const int* dst = ei + E;
    const int K = (N + 255) >> 8;          // dst-buckets of 256 nodes

    // workspace (floats):
    //   dinv[N] | big[64N] (tmp overlay during build; later g1|g2|rdot|z)
    //   | off[N] | epair[E] int2 | gcursor[K] | gstart[K+1]
    float* ws    = (float*)d_ws;
    float* dinv  = ws;
    float* big   = dinv + N;
    float* g1    = big;                            // 32N
    float* g2    = big + (size_t)32 * N;           // 16N
    float* rdot  = big + (size_t)48 * N;           // N
    float* z     = big + (size_t)49 * N;           // N
    int*   off   = (int*)(big + (size_t)64 * N);
    int2*  epair = (int2*)(off + N);
    int*   gcursor = (int*)(epair + E);
    int*   gstart  = gcursor + K;
    uint2* tmp   = (uint2*)big;                    // E uint2 <= 64N floats

    size_t need = ((size_t)66 * N + (size_t)2 * E + 2 * K + 2) * 4;
    if (ws_size < need || K > KMAXB || (size_t)E > (size_t)32 * N) return;

    hipMemsetAsync(gcursor, 0, (size_t)K * sizeof(int), stream);

    countA_kernel<<<(E + PA_CHUNK - 1) / PA_CHUNK, 512, 0, stream>>>(dst, gcursor, E, K);
    kscan_kernel<<<1, 64, 0, stream>>>(gcursor, gstart, gcursor, K, E);
    placeA_kernel<<<(E + PA_CHUNK - 1) / PA_CHUNK, 512, 0, stream>>>(
        src, dst, ew, tmp, gcursor, E, K);
    partB_kernel<<<K, 512, 0, stream>>>(tmp, gstart, epair, off, dinv, N);

    gemm1_kernel<<<(N + 31) / 32, TPB, 0, stream>>>(x, W1, dinv, g1, N);

    const int gblocks = (N + 4 * NPW - 1) / (4 * NPW);   // 4 waves x NPW nodes
    gather32_fused_kernel<<<gblocks, TPB, 0, stream>>>(
        off, epair, g1, dinv, b1, W2, fc2_w, g2, rdot, N, E);
    zprep_kernel<<<(N + TPB - 1) / TPB, TPB, 0, stream>>>(g2, fc1_w, z, N);
    final_scalar_kernel<<<gblocks, TPB, 0, stream>>>(
        off, epair, z, rdot, dinv, b2, fc1_w, fc1_b, fc2_w, fc2_b,
        (float*)d_out, N, E);
}